// Round 1
// baseline (2201.535 us; speedup 1.0000x reference)
//
#include <hip/hip_runtime.h>
#include <cstddef>

#define NN 50000
#define EE 1600000
#define IN_DIM 512
#define HID 256
#define OUT_DIM 40
#define KSTEPS 10
#define BN_EPS 1e-5f

// ---------------- degree (row) + histogram (col) ----------------
__global__ void k_deg_hist(const int* __restrict__ ei, float* __restrict__ deg,
                           int* __restrict__ cnt) {
    int e = blockIdx.x * blockDim.x + threadIdx.x;
    if (e >= EE) return;
    atomicAdd(&deg[ei[e]], 1.0f);        // row degree (float, exact small ints)
    atomicAdd(&cnt[ei[EE + e]], 1);      // col histogram for CSC build
}

// ---------------- deg -> dinv in place ----------------
__global__ void k_dinv(float* __restrict__ deg) {
    int i = blockIdx.x * blockDim.x + threadIdx.x;
    if (i >= NN) return;
    float d = deg[i];
    d = d < 1.0f ? 1.0f : d;
    deg[i] = 1.0f / sqrtf(d);
}

// ---------------- single-block exclusive scan: cnt -> ptr, cursor ----------------
__global__ __launch_bounds__(1024) void k_scan(const int* __restrict__ cnt,
                                               int* __restrict__ ptr,
                                               int* __restrict__ cursor) {
    __shared__ int partial[1024];
    __shared__ int base[1024];
    int tid = threadIdx.x;
    const int CH = (NN + 1023) / 1024;   // 49
    int st = tid * CH;
    int en = st + CH < NN ? st + CH : NN;
    int s = 0;
    for (int i = st; i < en; ++i) s += cnt[i];
    partial[tid] = s;
    __syncthreads();
    if (tid == 0) {
        int run = 0;
        for (int i = 0; i < 1024; ++i) { base[i] = run; run += partial[i]; }
    }
    __syncthreads();
    int run = base[tid];
    for (int i = st; i < en; ++i) {
        ptr[i] = run;
        cursor[i] = run;
        run += cnt[i];
    }
    if (tid == 1023) ptr[NN] = run;      // == EE
}

// ---------------- scatter edges into CSC buckets (fused norm) ----------------
__global__ void k_scatter(const int* __restrict__ ei, const float* __restrict__ dinv,
                          int* __restrict__ cursor, int* __restrict__ csr_src,
                          float* __restrict__ csr_nrm) {
    int e = blockIdx.x * blockDim.x + threadIdx.x;
    if (e >= EE) return;
    int r = ei[e];
    int c = ei[EE + e];
    int idx = atomicAdd(&cursor[c], 1);
    csr_src[idx] = r;
    csr_nrm[idx] = dinv[r] * dinv[c];
}

// ---------------- GEMM1: h = relu(BN(x @ W1^T + b1))  [NN x HID] ----------------
// 64x64 tile, 256 threads, 4x4 microtile, K-tile 16.
__global__ __launch_bounds__(256) void k_gemm1(const float* __restrict__ x,
                                               const float* __restrict__ W1,
                                               const float* __restrict__ b1,
                                               const float* __restrict__ bnw,
                                               const float* __restrict__ bnb,
                                               const float* __restrict__ bnm,
                                               const float* __restrict__ bnv,
                                               float* __restrict__ h) {
    __shared__ float As[16][64];
    __shared__ float Bs[16][64];
    int tid = threadIdx.x;
    int brow = blockIdx.x * 64;
    int bcol = blockIdx.y * 64;
    int ty = tid >> 4;            // 0..15 -> rows
    int tx = tid & 15;            // 0..15 -> cols
    int row_a = tid >> 2;         // 0..63
    int ka = (tid & 3) << 2;      // 0,4,8,12

    float acc[4][4] = {};
    bool arow_ok = (brow + row_a) < NN;
    const float* xa = x + (size_t)(brow + row_a) * IN_DIM + ka;
    const float* wb = W1 + (size_t)(bcol + row_a) * IN_DIM + ka;

    for (int kt = 0; kt < IN_DIM; kt += 16) {
        float4 av = make_float4(0.f, 0.f, 0.f, 0.f);
        if (arow_ok) av = *(const float4*)(xa + kt);
        float4 bv = *(const float4*)(wb + kt);
        As[ka + 0][row_a] = av.x; As[ka + 1][row_a] = av.y;
        As[ka + 2][row_a] = av.z; As[ka + 3][row_a] = av.w;
        Bs[ka + 0][row_a] = bv.x; Bs[ka + 1][row_a] = bv.y;
        Bs[ka + 2][row_a] = bv.z; Bs[ka + 3][row_a] = bv.w;
        __syncthreads();
#pragma unroll
        for (int kk = 0; kk < 16; ++kk) {
            float4 a = *(const float4*)&As[kk][ty * 4];
            float4 b = *(const float4*)&Bs[kk][tx * 4];
            acc[0][0] += a.x * b.x; acc[0][1] += a.x * b.y; acc[0][2] += a.x * b.z; acc[0][3] += a.x * b.w;
            acc[1][0] += a.y * b.x; acc[1][1] += a.y * b.y; acc[1][2] += a.y * b.z; acc[1][3] += a.y * b.w;
            acc[2][0] += a.z * b.x; acc[2][1] += a.z * b.y; acc[2][2] += a.z * b.z; acc[2][3] += a.z * b.w;
            acc[3][0] += a.w * b.x; acc[3][1] += a.w * b.y; acc[3][2] += a.w * b.z; acc[3][3] += a.w * b.w;
        }
        __syncthreads();
    }

    // BN + ReLU epilogue; per-column scale/offset
    float scl[4], off[4];
#pragma unroll
    for (int j = 0; j < 4; ++j) {
        int c = bcol + tx * 4 + j;
        float s = bnw[c] * rsqrtf(bnv[c] + BN_EPS);
        scl[j] = s;
        off[j] = (b1[c] - bnm[c]) * s + bnb[c];
    }
#pragma unroll
    for (int i = 0; i < 4; ++i) {
        int gr = brow + ty * 4 + i;
        if (gr >= NN) continue;
        float4 v;
        float v0 = acc[i][0] * scl[0] + off[0];
        float v1 = acc[i][1] * scl[1] + off[1];
        float v2 = acc[i][2] * scl[2] + off[2];
        float v3 = acc[i][3] * scl[3] + off[3];
        v.x = v0 > 0.f ? v0 : 0.f;
        v.y = v1 > 0.f ? v1 : 0.f;
        v.z = v2 > 0.f ? v2 : 0.f;
        v.w = v3 > 0.f ? v3 : 0.f;
        *(float4*)&h[(size_t)gr * HID + bcol + tx * 4] = v;
    }
}

// ---------------- GEMM2: z = h @ W2^T + b2; ping = z; out = gamma0 * z ----------------
__global__ __launch_bounds__(256) void k_gemm2(const float* __restrict__ h,
                                               const float* __restrict__ W2,
                                               const float* __restrict__ b2,
                                               const float* __restrict__ gamma,
                                               float* __restrict__ ping,
                                               float* __restrict__ out) {
    __shared__ float W2s[OUT_DIM * HID];  // 40 KiB
    int tid = threadIdx.x;
    for (int i = tid * 4; i < OUT_DIM * HID; i += 256 * 4) {
        *(float4*)&W2s[i] = *(const float4*)&W2[i];
    }
    __syncthreads();
    float g0 = gamma[0];
    int n0 = blockIdx.x * 64;
    for (int t = tid; t < 64 * OUT_DIM; t += 256) {
        int nl = t / OUT_DIM;
        int o  = t - nl * OUT_DIM;
        int n  = n0 + nl;
        if (n >= NN) continue;
        const float* hr = h + (size_t)n * HID;
        const float* wr = W2s + o * HID;
        float d = 0.f;
#pragma unroll 4
        for (int k = 0; k < HID; k += 4) {
            float4 hv = *(const float4*)(hr + k);
            float4 wv = *(const float4*)(wr + k);
            d += hv.x * wv.x + hv.y * wv.y + hv.z * wv.z + hv.w * wv.w;
        }
        d += b2[o];
        ping[(size_t)n * OUT_DIM + o] = d;
        out[(size_t)n * OUT_DIM + o] = g0 * d;
    }
}

// ---------------- one propagation step: nxt = A_norm @ cur; out += gamma[k]*nxt ----------------
// one wave per destination node, lane = feature (40 active of 64)
__global__ __launch_bounds__(256) void k_spmm(const int* __restrict__ ptr,
                                              const int* __restrict__ src,
                                              const float* __restrict__ nrm,
                                              const float* __restrict__ cur,
                                              float* __restrict__ nxt,
                                              float* __restrict__ out,
                                              const float* __restrict__ gamma, int k) {
    int wave = (blockIdx.x * blockDim.x + threadIdx.x) >> 6;
    int lane = threadIdx.x & 63;
    if (wave >= NN) return;
    int e0 = ptr[wave];
    int e1 = ptr[wave + 1];
    if (lane < OUT_DIM) {
        float acc = 0.f;
        for (int e = e0; e < e1; ++e) {
            acc += nrm[e] * cur[(size_t)src[e] * OUT_DIM + lane];
        }
        nxt[(size_t)wave * OUT_DIM + lane] = acc;
        out[(size_t)wave * OUT_DIM + lane] += gamma[k] * acc;
    }
}

extern "C" void kernel_launch(void* const* d_in, const int* in_sizes, int n_in,
                              void* d_out, int out_size, void* d_ws, size_t ws_size,
                              hipStream_t stream) {
    const float* x   = (const float*)d_in[0];
    const int*   ei  = (const int*)d_in[1];
    const float* W1  = (const float*)d_in[2];
    const float* b1  = (const float*)d_in[3];
    const float* bnw = (const float*)d_in[4];
    const float* bnb = (const float*)d_in[5];
    const float* bnm = (const float*)d_in[6];
    const float* bnv = (const float*)d_in[7];
    const float* W2  = (const float*)d_in[8];
    const float* b2  = (const float*)d_in[9];
    const float* gamma = (const float*)d_in[10];
    float* out = (float*)d_out;

    char* ws = (char*)d_ws;
    const size_t A = 256;
    auto pad = [&](size_t b) { return (b + A - 1) / A * A; };
    size_t off = 0;
    float* deg    = (float*)(ws + off); off += pad((size_t)NN * 4);
    int*   cnt    = (int*)  (ws + off); off += pad((size_t)NN * 4);
    int*   ptr    = (int*)  (ws + off); off += pad((size_t)(NN + 1) * 4);
    int*   cursor = (int*)  (ws + off); off += pad((size_t)NN * 4);
    int*   csrsrc = (int*)  (ws + off); off += pad((size_t)EE * 4);
    float* csrnrm = (float*)(ws + off); off += pad((size_t)EE * 4);
    float* h      = (float*)(ws + off); off += pad((size_t)NN * HID * 4);
    float* ping   = (float*)(ws + off); off += pad((size_t)NN * OUT_DIM * 4);
    float* pong   = (float*)(ws + off); off += pad((size_t)NN * OUT_DIM * 4);

    // zero deg + cnt (must be per-call: determinism)
    hipMemsetAsync(deg, 0, (size_t)NN * 4, stream);
    hipMemsetAsync(cnt, 0, (size_t)NN * 4, stream);

    // graph structure
    k_deg_hist<<<(EE + 255) / 256, 256, 0, stream>>>(ei, deg, cnt);
    k_dinv<<<(NN + 255) / 256, 256, 0, stream>>>(deg);
    k_scan<<<1, 1024, 0, stream>>>(cnt, ptr, cursor);
    k_scatter<<<(EE + 255) / 256, 256, 0, stream>>>(ei, deg, cursor, csrsrc, csrnrm);

    // MLP
    dim3 g1((NN + 63) / 64, HID / 64);
    k_gemm1<<<g1, 256, 0, stream>>>(x, W1, b1, bnw, bnb, bnm, bnv, h);
    k_gemm2<<<(NN + 63) / 64, 256, 0, stream>>>(h, W2, b2, gamma, ping, out);

    // K propagation steps, ping-pong
    float* cur = ping;
    float* nxt = pong;
    for (int k = 1; k <= KSTEPS; ++k) {
        k_spmm<<<(NN * 64 + 255) / 256, 256, 0, stream>>>(ptr, csrsrc, csrnrm,
                                                          cur, nxt, out, gamma, k);
        float* t = cur; cur = nxt; nxt = t;
    }
}

// Round 2
// 1208.241 us; speedup vs baseline: 1.8221x; 1.8221x over previous
//
#include <hip/hip_runtime.h>
#include <cstddef>

#define NN 50000
#define EE 1600000
#define IN_DIM 512
#define HID 256
#define OUT_DIM 40
#define KSTEPS 10
#define BN_EPS 1e-5f

// ---------------- degree (row) + histogram (col) ----------------
__global__ void k_deg_hist(const int* __restrict__ ei, float* __restrict__ deg,
                           int* __restrict__ cnt) {
    int e = blockIdx.x * blockDim.x + threadIdx.x;
    if (e >= EE) return;
    atomicAdd(&deg[ei[e]], 1.0f);        // row degree (float, exact small ints)
    atomicAdd(&cnt[ei[EE + e]], 1);      // col histogram for CSC build
}

// ---------------- deg -> dinv in place ----------------
__global__ void k_dinv(float* __restrict__ deg) {
    int i = blockIdx.x * blockDim.x + threadIdx.x;
    if (i >= NN) return;
    float d = deg[i];
    d = d < 1.0f ? 1.0f : d;
    deg[i] = 1.0f / sqrtf(d);
}

// ---------------- single-block exclusive scan: cnt -> ptr, cursor ----------------
__global__ __launch_bounds__(1024) void k_scan(const int* __restrict__ cnt,
                                               int* __restrict__ ptr,
                                               int* __restrict__ cursor) {
    __shared__ int partial[1024];
    __shared__ int base[1024];
    int tid = threadIdx.x;
    const int CH = (NN + 1023) / 1024;   // 49
    int st = tid * CH;
    int en = st + CH < NN ? st + CH : NN;
    int s = 0;
    for (int i = st; i < en; ++i) s += cnt[i];
    partial[tid] = s;
    __syncthreads();
    if (tid == 0) {
        int run = 0;
        for (int i = 0; i < 1024; ++i) { base[i] = run; run += partial[i]; }
    }
    __syncthreads();
    int run = base[tid];
    for (int i = st; i < en; ++i) {
        ptr[i] = run;
        cursor[i] = run;
        run += cnt[i];
    }
    if (tid == 1023) ptr[NN] = run;      // == EE
}

// ---------------- scatter edges into CSC buckets (fused norm) ----------------
__global__ void k_scatter(const int* __restrict__ ei, const float* __restrict__ dinv,
                          int* __restrict__ cursor, int* __restrict__ csr_src,
                          float* __restrict__ csr_nrm) {
    int e = blockIdx.x * blockDim.x + threadIdx.x;
    if (e >= EE) return;
    int r = ei[e];
    int c = ei[EE + e];
    int idx = atomicAdd(&cursor[c], 1);
    csr_src[idx] = r;
    csr_nrm[idx] = dinv[r] * dinv[c];
}

// ---------------- GEMM1: h = relu(BN(x @ W1^T + b1))  [NN x HID] ----------------
// 64x64 tile, 256 threads, 4x4 microtile, K-tile 16.
__global__ __launch_bounds__(256) void k_gemm1(const float* __restrict__ x,
                                               const float* __restrict__ W1,
                                               const float* __restrict__ b1,
                                               const float* __restrict__ bnw,
                                               const float* __restrict__ bnb,
                                               const float* __restrict__ bnm,
                                               const float* __restrict__ bnv,
                                               float* __restrict__ h) {
    __shared__ float As[16][64];
    __shared__ float Bs[16][64];
    int tid = threadIdx.x;
    int brow = blockIdx.x * 64;
    int bcol = blockIdx.y * 64;
    int ty = tid >> 4;            // 0..15 -> rows
    int tx = tid & 15;            // 0..15 -> cols
    int row_a = tid >> 2;         // 0..63
    int ka = (tid & 3) << 2;      // 0,4,8,12

    float acc[4][4] = {};
    bool arow_ok = (brow + row_a) < NN;
    const float* xa = x + (size_t)(brow + row_a) * IN_DIM + ka;
    const float* wb = W1 + (size_t)(bcol + row_a) * IN_DIM + ka;

    for (int kt = 0; kt < IN_DIM; kt += 16) {
        float4 av = make_float4(0.f, 0.f, 0.f, 0.f);
        if (arow_ok) av = *(const float4*)(xa + kt);
        float4 bv = *(const float4*)(wb + kt);
        As[ka + 0][row_a] = av.x; As[ka + 1][row_a] = av.y;
        As[ka + 2][row_a] = av.z; As[ka + 3][row_a] = av.w;
        Bs[ka + 0][row_a] = bv.x; Bs[ka + 1][row_a] = bv.y;
        Bs[ka + 2][row_a] = bv.z; Bs[ka + 3][row_a] = bv.w;
        __syncthreads();
#pragma unroll
        for (int kk = 0; kk < 16; ++kk) {
            float4 a = *(const float4*)&As[kk][ty * 4];
            float4 b = *(const float4*)&Bs[kk][tx * 4];
            acc[0][0] += a.x * b.x; acc[0][1] += a.x * b.y; acc[0][2] += a.x * b.z; acc[0][3] += a.x * b.w;
            acc[1][0] += a.y * b.x; acc[1][1] += a.y * b.y; acc[1][2] += a.y * b.z; acc[1][3] += a.y * b.w;
            acc[2][0] += a.z * b.x; acc[2][1] += a.z * b.y; acc[2][2] += a.z * b.z; acc[2][3] += a.z * b.w;
            acc[3][0] += a.w * b.x; acc[3][1] += a.w * b.y; acc[3][2] += a.w * b.z; acc[3][3] += a.w * b.w;
        }
        __syncthreads();
    }

    // BN + ReLU epilogue; per-column scale/offset
    float scl[4], off[4];
#pragma unroll
    for (int j = 0; j < 4; ++j) {
        int c = bcol + tx * 4 + j;
        float s = bnw[c] * rsqrtf(bnv[c] + BN_EPS);
        scl[j] = s;
        off[j] = (b1[c] - bnm[c]) * s + bnb[c];
    }
#pragma unroll
    for (int i = 0; i < 4; ++i) {
        int gr = brow + ty * 4 + i;
        if (gr >= NN) continue;
        float4 v;
        float v0 = acc[i][0] * scl[0] + off[0];
        float v1 = acc[i][1] * scl[1] + off[1];
        float v2 = acc[i][2] * scl[2] + off[2];
        float v3 = acc[i][3] * scl[3] + off[3];
        v.x = v0 > 0.f ? v0 : 0.f;
        v.y = v1 > 0.f ? v1 : 0.f;
        v.z = v2 > 0.f ? v2 : 0.f;
        v.w = v3 > 0.f ? v3 : 0.f;
        *(float4*)&h[(size_t)gr * HID + bcol + tx * 4] = v;
    }
}

// ---------------- GEMM2: z = h @ W2^T + b2; ping = z; out = gamma0 * z ----------------
// Thread-per-node, W2 staged TRANSPOSED in LDS -> all lanes broadcast-read the
// same LDS address (zero bank conflicts). 40 fp32 accumulators per thread.
__global__ __launch_bounds__(256) void k_gemm2(const float* __restrict__ h,
                                               const float* __restrict__ W2,
                                               const float* __restrict__ b2,
                                               const float* __restrict__ gamma,
                                               float* __restrict__ ping,
                                               float* __restrict__ out) {
    __shared__ float W2T[HID * OUT_DIM];  // [k][o], 40 KiB
    int tid = threadIdx.x;
    for (int i = tid; i < HID * OUT_DIM; i += 256) {
        int o = i / HID;
        int k = i - o * HID;
        W2T[k * OUT_DIM + o] = W2[i];   // W2 flat is [o][k]
    }
    __syncthreads();
    int n = blockIdx.x * 256 + tid;
    if (n >= NN) return;

    float4 acc[10];
#pragma unroll
    for (int o4 = 0; o4 < 10; ++o4) acc[o4] = *(const float4*)&b2[o4 * 4];

    const float4* hr = (const float4*)(h + (size_t)n * HID);
    const float4* wt = (const float4*)W2T;
    for (int j = 0; j < HID / 4; ++j) {
        float4 hv = hr[j];
#pragma unroll
        for (int c = 0; c < 4; ++c) {
            float hk = (c == 0) ? hv.x : (c == 1) ? hv.y : (c == 2) ? hv.z : hv.w;
            const float4* wr = wt + (size_t)(j * 4 + c) * 10;
#pragma unroll
            for (int o4 = 0; o4 < 10; ++o4) {
                float4 w = wr[o4];
                acc[o4].x += hk * w.x;
                acc[o4].y += hk * w.y;
                acc[o4].z += hk * w.z;
                acc[o4].w += hk * w.w;
            }
        }
    }
    float g0 = gamma[0];
    float4* pp = (float4*)(ping + (size_t)n * OUT_DIM);
    float4* op = (float4*)(out + (size_t)n * OUT_DIM);
#pragma unroll
    for (int o4 = 0; o4 < 10; ++o4) {
        pp[o4] = acc[o4];
        float4 g;
        g.x = g0 * acc[o4].x; g.y = g0 * acc[o4].y;
        g.z = g0 * acc[o4].z; g.w = g0 * acc[o4].w;
        op[o4] = g;
    }
}

// ---------------- one propagation step: nxt = A_norm @ cur; out += gamma[k]*nxt ----------------
// one wave per destination node, lane = feature (40 active of 64); 4-way edge
// unroll with independent partial sums to break the serial FMA/load chain.
__global__ __launch_bounds__(256) void k_spmm(const int* __restrict__ ptr,
                                              const int* __restrict__ src,
                                              const float* __restrict__ nrm,
                                              const float* __restrict__ cur,
                                              float* __restrict__ nxt,
                                              float* __restrict__ out,
                                              const float* __restrict__ gamma, int k) {
    int wave = (blockIdx.x * blockDim.x + threadIdx.x) >> 6;
    int lane = threadIdx.x & 63;
    if (wave >= NN) return;
    int e0 = ptr[wave];
    int e1 = ptr[wave + 1];
    if (lane < OUT_DIM) {
        float a0 = 0.f, a1 = 0.f, a2 = 0.f, a3 = 0.f;
        int e = e0;
        for (; e + 3 < e1; e += 4) {
            int s0 = src[e], s1 = src[e + 1], s2 = src[e + 2], s3 = src[e + 3];
            float w0 = nrm[e], w1 = nrm[e + 1], w2 = nrm[e + 2], w3 = nrm[e + 3];
            a0 += w0 * cur[(size_t)s0 * OUT_DIM + lane];
            a1 += w1 * cur[(size_t)s1 * OUT_DIM + lane];
            a2 += w2 * cur[(size_t)s2 * OUT_DIM + lane];
            a3 += w3 * cur[(size_t)s3 * OUT_DIM + lane];
        }
        for (; e < e1; ++e) {
            a0 += nrm[e] * cur[(size_t)src[e] * OUT_DIM + lane];
        }
        float acc = (a0 + a1) + (a2 + a3);
        nxt[(size_t)wave * OUT_DIM + lane] = acc;
        out[(size_t)wave * OUT_DIM + lane] += gamma[k] * acc;
    }
}

extern "C" void kernel_launch(void* const* d_in, const int* in_sizes, int n_in,
                              void* d_out, int out_size, void* d_ws, size_t ws_size,
                              hipStream_t stream) {
    const float* x   = (const float*)d_in[0];
    const int*   ei  = (const int*)d_in[1];
    const float* W1  = (const float*)d_in[2];
    const float* b1  = (const float*)d_in[3];
    const float* bnw = (const float*)d_in[4];
    const float* bnb = (const float*)d_in[5];
    const float* bnm = (const float*)d_in[6];
    const float* bnv = (const float*)d_in[7];
    const float* W2  = (const float*)d_in[8];
    const float* b2  = (const float*)d_in[9];
    const float* gamma = (const float*)d_in[10];
    float* out = (float*)d_out;

    char* ws = (char*)d_ws;
    const size_t A = 256;
    auto pad = [&](size_t b) { return (b + A - 1) / A * A; };
    size_t off = 0;
    float* deg    = (float*)(ws + off); off += pad((size_t)NN * 4);
    int*   cnt    = (int*)  (ws + off); off += pad((size_t)NN * 4);
    int*   ptr    = (int*)  (ws + off); off += pad((size_t)(NN + 1) * 4);
    int*   cursor = (int*)  (ws + off); off += pad((size_t)NN * 4);
    int*   csrsrc = (int*)  (ws + off); off += pad((size_t)EE * 4);
    float* csrnrm = (float*)(ws + off); off += pad((size_t)EE * 4);
    float* h      = (float*)(ws + off); off += pad((size_t)NN * HID * 4);
    float* ping   = (float*)(ws + off); off += pad((size_t)NN * OUT_DIM * 4);
    float* pong   = (float*)(ws + off); off += pad((size_t)NN * OUT_DIM * 4);

    // zero deg + cnt (must be per-call: determinism)
    hipMemsetAsync(deg, 0, (size_t)NN * 4, stream);
    hipMemsetAsync(cnt, 0, (size_t)NN * 4, stream);

    // graph structure
    k_deg_hist<<<(EE + 255) / 256, 256, 0, stream>>>(ei, deg, cnt);
    k_dinv<<<(NN + 255) / 256, 256, 0, stream>>>(deg);
    k_scan<<<1, 1024, 0, stream>>>(cnt, ptr, cursor);
    k_scatter<<<(EE + 255) / 256, 256, 0, stream>>>(ei, deg, cursor, csrsrc, csrnrm);

    // MLP
    dim3 g1((NN + 63) / 64, HID / 64);
    k_gemm1<<<g1, 256, 0, stream>>>(x, W1, b1, bnw, bnb, bnm, bnv, h);
    k_gemm2<<<(NN + 255) / 256, 256, 0, stream>>>(h, W2, b2, gamma, ping, out);

    // K propagation steps, ping-pong
    float* cur = ping;
    float* nxt = pong;
    for (int k = 1; k <= KSTEPS; ++k) {
        k_spmm<<<(NN * 64 + 255) / 256, 256, 0, stream>>>(ptr, csrsrc, csrnrm,
                                                          cur, nxt, out, gamma, k);
        float* t = cur; cur = nxt; nxt = t;
    }
}

// Round 3
// 1065.616 us; speedup vs baseline: 2.0660x; 1.1338x over previous
//
#include <hip/hip_runtime.h>
#include <cstddef>

#define NN 50000
#define EE 1600000
#define IN_DIM 512
#define HID 256
#define OUT_DIM 40
#define KSTEPS 10
#define BN_EPS 1e-5f

typedef __attribute__((ext_vector_type(8))) short short8;
typedef __attribute__((ext_vector_type(4))) float f32x4;

__device__ inline unsigned short bf16_rne(float v) {
    union { float f; unsigned u; } c; c.f = v;
    unsigned u = c.u;
    unsigned r = u + 0x7fff + ((u >> 16) & 1);
    return (unsigned short)(r >> 16);
}
__device__ inline float bf16_to_f(unsigned short h) {
    union { unsigned u; float f; } c; c.u = ((unsigned)h) << 16;
    return c.f;
}

// ---------------- degree (row) + histogram (col) ----------------
__global__ void k_deg_hist(const int* __restrict__ ei, float* __restrict__ deg,
                           int* __restrict__ cnt) {
    int e = blockIdx.x * blockDim.x + threadIdx.x;
    if (e >= EE) return;
    atomicAdd(&deg[ei[e]], 1.0f);
    atomicAdd(&cnt[ei[EE + e]], 1);
}

// ---------------- deg -> dinv in place ----------------
__global__ void k_dinv(float* __restrict__ deg) {
    int i = blockIdx.x * blockDim.x + threadIdx.x;
    if (i >= NN) return;
    float d = deg[i];
    d = d < 1.0f ? 1.0f : d;
    deg[i] = 1.0f / sqrtf(d);
}

// ---------------- parallel exclusive scan: cnt -> ptr, cursor ----------------
__global__ __launch_bounds__(1024) void k_scan(const int* __restrict__ cnt,
                                               int* __restrict__ ptr,
                                               int* __restrict__ cursor) {
    __shared__ int wsum[16];
    int tid = threadIdx.x;
    const int CH = (NN + 1023) / 1024;   // 49
    int st = tid * CH;
    int en = st + CH < NN ? st + CH : NN;
    int s = 0;
    for (int i = st; i < en; ++i) s += cnt[i];
    int lane = tid & 63, w = tid >> 6;
    // inclusive scan within wave
    int v = s;
    for (int d = 1; d < 64; d <<= 1) {
        int t = __shfl_up(v, d);
        if (lane >= d) v += t;
    }
    if (lane == 63) wsum[w] = v;
    __syncthreads();
    if (w == 0) {
        int t = (lane < 16) ? wsum[lane] : 0;
        for (int d = 1; d < 16; d <<= 1) {
            int u = __shfl_up(t, d);
            if (lane >= d) t += u;
        }
        if (lane < 16) wsum[lane] = t;
    }
    __syncthreads();
    int base = (w > 0 ? wsum[w - 1] : 0) + (v - s);  // exclusive prefix of this chunk
    int run = base;
    for (int i = st; i < en; ++i) {
        ptr[i] = run;
        cursor[i] = run;
        run += cnt[i];
    }
    if (tid == 1023) ptr[NN] = run;
}

// ---------------- scatter edges into CSC buckets, packed (src, norm) ----------------
__global__ void k_scatter(const int* __restrict__ ei, const float* __restrict__ dinv,
                          int* __restrict__ cursor, int2* __restrict__ epack) {
    int e = blockIdx.x * blockDim.x + threadIdx.x;
    if (e >= EE) return;
    int r = ei[e];
    int c = ei[EE + e];
    int idx = atomicAdd(&cursor[c], 1);
    int2 p;
    p.x = r;
    p.y = __float_as_int(dinv[r] * dinv[c]);
    epack[idx] = p;
}

// ---------------- W1 -> bf16 hi/lo split (once per call) ----------------
__global__ void k_w1split(const float* __restrict__ W1, unsigned short* __restrict__ w1h,
                          unsigned short* __restrict__ w1l) {
    int i = blockIdx.x * blockDim.x + threadIdx.x;
    if (i >= HID * IN_DIM) return;
    float v = W1[i];
    unsigned short h = bf16_rne(v);
    unsigned short l = bf16_rne(v - bf16_to_f(h));
    w1h[i] = h;
    w1l[i] = l;
}

// ---------------- GEMM1 via split-bf16 MFMA: h = relu(BN(x @ W1^T + b1)) ----------------
// BM=64, BN=256 (full width -> x read once), BK=64, 8 waves, wave tile 32x64.
// 3-product split: xh*Wh + xh*Wl + xl*Wh, fp32 accumulate.
#define BM 64
#define BK 64
__global__ __launch_bounds__(512) void k_gemm1m(const float* __restrict__ x,
                                                const unsigned short* __restrict__ w1h,
                                                const unsigned short* __restrict__ w1l,
                                                const float* __restrict__ b1,
                                                const float* __restrict__ bnw,
                                                const float* __restrict__ bnb,
                                                const float* __restrict__ bnm,
                                                const float* __restrict__ bnv,
                                                float* __restrict__ h) {
    __shared__ __align__(16) unsigned short Ah[BM * BK];
    __shared__ __align__(16) unsigned short Al[BM * BK];
    __shared__ __align__(16) unsigned short Bh[HID * BK];
    __shared__ __align__(16) unsigned short Bl[HID * BK];
    int tid = threadIdx.x;
    int lane = tid & 63;
    int wid = tid >> 6;
    int wm = wid >> 2;           // 0..1
    int wn = wid & 3;            // 0..3
    int brow = blockIdx.x * BM;

    // A staging: thread t -> row ra (64 rows), 8 floats at col ca
    int ra = tid >> 3, ca = (tid & 7) * 8;
    // B staging: thread t -> row rb (256 rows), 32 bf16 at col cb
    int rb = tid >> 1, cb = (tid & 1) * 32;

    bool rok = (brow + ra) < NN;
    const float* xa = x + (size_t)(brow + ra) * IN_DIM + ca;
    const unsigned short* bhp = w1h + (size_t)rb * IN_DIM + cb;
    const unsigned short* blp = w1l + (size_t)rb * IN_DIM + cb;

    // precomputed swizzled LDS byte offsets
    int abyte = (ra * BK + ca) * 2; abyte ^= (ra & 7) << 4;
    int bbyte0 = (rb * BK + cb) * 2; // 4 chunks of 16B at +0,16,32,48, each swizzled
    int bsw = (rb & 7) << 4;

    f32x4 acc[2][4];
#pragma unroll
    for (int i = 0; i < 2; ++i)
#pragma unroll
        for (int j = 0; j < 4; ++j) acc[i][j] = (f32x4){0.f, 0.f, 0.f, 0.f};

    // per-lane fragment read offsets
    int frow_a = wm * 32 + (lane & 15);        // + mi*16
    int frow_b = wn * 64 + (lane & 15);        // + ni*16
    int fk = (lane >> 4) * 16;                 // byte offset of 8-bf16 group, + kk*64

    for (int kt = 0; kt < IN_DIM; kt += BK) {
        // global loads first (overlap w/ previous compute)
        float4 v0 = make_float4(0.f, 0.f, 0.f, 0.f), v1 = v0;
        if (rok) {
            v0 = *(const float4*)(xa + kt);
            v1 = *(const float4*)(xa + kt + 4);
        }
        short8 gb_h[4], gb_l[4];
#pragma unroll
        for (int q = 0; q < 4; ++q) {
            gb_h[q] = *(const short8*)(bhp + kt + q * 8);
            gb_l[q] = *(const short8*)(blp + kt + q * 8);
        }
        __syncthreads();   // previous compute done, LDS reusable
        // convert A to hi/lo bf16
        union { unsigned short u[8]; short8 v; } uh, ul;
        float vv[8] = {v0.x, v0.y, v0.z, v0.w, v1.x, v1.y, v1.z, v1.w};
#pragma unroll
        for (int j = 0; j < 8; ++j) {
            unsigned short hh = bf16_rne(vv[j]);
            uh.u[j] = hh;
            ul.u[j] = bf16_rne(vv[j] - bf16_to_f(hh));
        }
        *(short8*)((char*)Ah + abyte) = uh.v;
        *(short8*)((char*)Al + abyte) = ul.v;
#pragma unroll
        for (int q = 0; q < 4; ++q) {
            int bb = (bbyte0 + q * 16) ^ bsw;
            *(short8*)((char*)Bh + bb) = gb_h[q];
            *(short8*)((char*)Bl + bb) = gb_l[q];
        }
        __syncthreads();   // tiles ready

#pragma unroll
        for (int kk = 0; kk < 2; ++kk) {
            short8 afh[2], afl[2];
#pragma unroll
            for (int mi = 0; mi < 2; ++mi) {
                int row = frow_a + mi * 16;
                int byte = (row * BK * 2 + kk * 64 + fk) ^ ((row & 7) << 4);
                afh[mi] = *(short8*)((char*)Ah + byte);
                afl[mi] = *(short8*)((char*)Al + byte);
            }
#pragma unroll
            for (int ni = 0; ni < 4; ++ni) {
                int row = frow_b + ni * 16;
                int byte = (row * BK * 2 + kk * 64 + fk) ^ ((row & 7) << 4);
                short8 bh = *(short8*)((char*)Bh + byte);
                short8 bl = *(short8*)((char*)Bl + byte);
#pragma unroll
                for (int mi = 0; mi < 2; ++mi) {
                    acc[mi][ni] = __builtin_amdgcn_mfma_f32_16x16x32_bf16(afh[mi], bh, acc[mi][ni], 0, 0, 0);
                    acc[mi][ni] = __builtin_amdgcn_mfma_f32_16x16x32_bf16(afl[mi], bh, acc[mi][ni], 0, 0, 0);
                    acc[mi][ni] = __builtin_amdgcn_mfma_f32_16x16x32_bf16(afh[mi], bl, acc[mi][ni], 0, 0, 0);
                }
            }
        }
    }

    // epilogue: BN + ReLU; C/D layout col=lane&15, row=(lane>>4)*4+j
    int cbase = wn * 64 + (lane & 15);
    float scl[4], off[4];
#pragma unroll
    for (int ni = 0; ni < 4; ++ni) {
        int c = cbase + ni * 16;
        float s = bnw[c] * rsqrtf(bnv[c] + BN_EPS);
        scl[ni] = s;
        off[ni] = (b1[c] - bnm[c]) * s + bnb[c];
    }
#pragma unroll
    for (int mi = 0; mi < 2; ++mi) {
        int r0 = brow + wm * 32 + mi * 16 + ((lane >> 4) << 2);
#pragma unroll
        for (int ni = 0; ni < 4; ++ni) {
            int c = cbase + ni * 16;
#pragma unroll
            for (int j = 0; j < 4; ++j) {
                int r = r0 + j;
                if (r < NN) {
                    float v = acc[mi][ni][j] * scl[ni] + off[ni];
                    h[(size_t)r * HID + c] = v > 0.f ? v : 0.f;
                }
            }
        }
    }
}

// ---------------- GEMM2: z = h @ W2^T + b2; ping = z; out = gamma0 * z ----------------
__global__ __launch_bounds__(256) void k_gemm2(const float* __restrict__ h,
                                               const float* __restrict__ W2,
                                               const float* __restrict__ b2,
                                               const float* __restrict__ gamma,
                                               float* __restrict__ ping,
                                               float* __restrict__ out) {
    __shared__ float W2T[HID * OUT_DIM];  // [k][o], 40 KiB
    int tid = threadIdx.x;
    for (int i = tid; i < HID * OUT_DIM; i += 256) {
        int o = i / HID;
        int k = i - o * HID;
        W2T[k * OUT_DIM + o] = W2[i];
    }
    __syncthreads();
    int n = blockIdx.x * 256 + tid;
    if (n >= NN) return;

    float4 acc[10];
#pragma unroll
    for (int o4 = 0; o4 < 10; ++o4) acc[o4] = *(const float4*)&b2[o4 * 4];

    const float4* hr = (const float4*)(h + (size_t)n * HID);
    const float4* wt = (const float4*)W2T;
    for (int j = 0; j < HID / 4; ++j) {
        float4 hv = hr[j];
#pragma unroll
        for (int c = 0; c < 4; ++c) {
            float hk = (c == 0) ? hv.x : (c == 1) ? hv.y : (c == 2) ? hv.z : hv.w;
            const float4* wr = wt + (size_t)(j * 4 + c) * 10;
#pragma unroll
            for (int o4 = 0; o4 < 10; ++o4) {
                float4 w = wr[o4];
                acc[o4].x += hk * w.x;
                acc[o4].y += hk * w.y;
                acc[o4].z += hk * w.z;
                acc[o4].w += hk * w.w;
            }
        }
    }
    float g0 = gamma[0];
    float4* pp = (float4*)(ping + (size_t)n * OUT_DIM);
    float4* op = (float4*)(out + (size_t)n * OUT_DIM);
#pragma unroll
    for (int o4 = 0; o4 < 10; ++o4) {
        pp[o4] = acc[o4];
        float4 g;
        g.x = g0 * acc[o4].x; g.y = g0 * acc[o4].y;
        g.z = g0 * acc[o4].z; g.w = g0 * acc[o4].w;
        op[o4] = g;
    }
}

// ---------------- one propagation step: nxt = A_norm @ cur; out += gamma[k]*nxt ----------------
__global__ __launch_bounds__(256) void k_spmm(const int* __restrict__ ptr,
                                              const int2* __restrict__ epack,
                                              const float* __restrict__ cur,
                                              float* __restrict__ nxt,
                                              float* __restrict__ out,
                                              const float* __restrict__ gamma, int k) {
    int wave = (blockIdx.x * blockDim.x + threadIdx.x) >> 6;
    int lane = threadIdx.x & 63;
    if (wave >= NN) return;
    int e0 = ptr[wave];
    int e1 = ptr[wave + 1];
    if (lane < OUT_DIM) {
        float a0 = 0.f, a1 = 0.f, a2 = 0.f, a3 = 0.f;
        int e = e0;
        for (; e + 3 < e1; e += 4) {
            int2 p0 = epack[e], p1 = epack[e + 1], p2 = epack[e + 2], p3 = epack[e + 3];
            a0 += __int_as_float(p0.y) * cur[(size_t)p0.x * OUT_DIM + lane];
            a1 += __int_as_float(p1.y) * cur[(size_t)p1.x * OUT_DIM + lane];
            a2 += __int_as_float(p2.y) * cur[(size_t)p2.x * OUT_DIM + lane];
            a3 += __int_as_float(p3.y) * cur[(size_t)p3.x * OUT_DIM + lane];
        }
        for (; e < e1; ++e) {
            int2 p = epack[e];
            a0 += __int_as_float(p.y) * cur[(size_t)p.x * OUT_DIM + lane];
        }
        float acc = (a0 + a1) + (a2 + a3);
        nxt[(size_t)wave * OUT_DIM + lane] = acc;
        out[(size_t)wave * OUT_DIM + lane] += gamma[k] * acc;
    }
}

extern "C" void kernel_launch(void* const* d_in, const int* in_sizes, int n_in,
                              void* d_out, int out_size, void* d_ws, size_t ws_size,
                              hipStream_t stream) {
    const float* x   = (const float*)d_in[0];
    const int*   ei  = (const int*)d_in[1];
    const float* W1  = (const float*)d_in[2];
    const float* b1  = (const float*)d_in[3];
    const float* bnw = (const float*)d_in[4];
    const float* bnb = (const float*)d_in[5];
    const float* bnm = (const float*)d_in[6];
    const float* bnv = (const float*)d_in[7];
    const float* W2  = (const float*)d_in[8];
    const float* b2  = (const float*)d_in[9];
    const float* gamma = (const float*)d_in[10];
    float* out = (float*)d_out;

    char* ws = (char*)d_ws;
    const size_t A = 256;
    auto pad = [&](size_t b) { return (b + A - 1) / A * A; };
    size_t off = 0;
    float* deg    = (float*)(ws + off); off += pad((size_t)NN * 4);
    int*   cnt    = (int*)  (ws + off); off += pad((size_t)NN * 4);
    int*   ptr    = (int*)  (ws + off); off += pad((size_t)(NN + 1) * 4);
    int*   cursor = (int*)  (ws + off); off += pad((size_t)NN * 4);
    int2*  epack  = (int2*) (ws + off); off += pad((size_t)EE * 8);
    float* h      = (float*)(ws + off); off += pad((size_t)NN * HID * 4);
    float* ping   = (float*)(ws + off); off += pad((size_t)NN * OUT_DIM * 4);
    float* pong   = (float*)(ws + off); off += pad((size_t)NN * OUT_DIM * 4);
    unsigned short* w1h = (unsigned short*)(ws + off); off += pad((size_t)HID * IN_DIM * 2);
    unsigned short* w1l = (unsigned short*)(ws + off); off += pad((size_t)HID * IN_DIM * 2);

    hipMemsetAsync(deg, 0, (size_t)NN * 4, stream);
    hipMemsetAsync(cnt, 0, (size_t)NN * 4, stream);

    // graph structure
    k_deg_hist<<<(EE + 255) / 256, 256, 0, stream>>>(ei, deg, cnt);
    k_dinv<<<(NN + 255) / 256, 256, 0, stream>>>(deg);
    k_scan<<<1, 1024, 0, stream>>>(cnt, ptr, cursor);
    k_scatter<<<(EE + 255) / 256, 256, 0, stream>>>(ei, deg, cursor, epack);

    // MLP
    k_w1split<<<(HID * IN_DIM + 255) / 256, 256, 0, stream>>>(W1, w1h, w1l);
    k_gemm1m<<<(NN + BM - 1) / BM, 512, 0, stream>>>(x, w1h, w1l, b1, bnw, bnb, bnm, bnv, h);
    k_gemm2<<<(NN + 255) / 256, 256, 0, stream>>>(h, W2, b2, gamma, ping, out);

    // K propagation steps, ping-pong
    float* cur = ping;
    float* nxt = pong;
    for (int k = 1; k <= KSTEPS; ++k) {
        k_spmm<<<(NN * 64 + 255) / 256, 256, 0, stream>>>(ptr, epack, cur, nxt, out, gamma, k);
        float* t = cur; cur = nxt; nxt = t;
    }
}